// Round 3
// baseline (286.222 us; speedup 1.0000x reference)
//
#include <hip/hip_runtime.h>
#include <cstdint>

#define BB 2048
#define TT 200
#define DD 128
#define H1 128
#define H2 64
#define MASK_PAD -4294967295.0f

typedef __attribute__((ext_vector_type(8))) short short8;
typedef __attribute__((ext_vector_type(4))) float floatx4;

static __device__ __forceinline__ unsigned short f2bf(float x) {
  union { float f; unsigned int u; } v; v.f = x;
  unsigned int r = v.u + 0x7FFF + ((v.u >> 16) & 1);  // RNE
  return (unsigned short)(r >> 16);
}

// ---------------------------------------------------------------------------
// Fold kernel -> ws:
//   Wqac[d][h] = W0a[d][h] + W0c[d][h]          fp32 [128][128] @ float 0
//   WkT [h][d] = (W0b - W0c)[d][h]              fp32 [128][128] @ float 16384
//   WdT [h][d] = W0d[d][h]                      fp32 [128][128] @ float 32768
//   W1tb[g][h] = bf16(W1[h][g])                 bf16 [64][128]  @ float 49152
// ---------------------------------------------------------------------------
__global__ void din_fold(const float* __restrict__ W0,
                         const float* __restrict__ W1,
                         float* __restrict__ ws) {
  int i = blockIdx.x * blockDim.x + threadIdx.x;
  if (i < 16384) {
    int d = i >> 7, h = i & 127;
    ws[i] = W0[d * 128 + h] + W0[(256 + d) * 128 + h];
  } else if (i < 32768) {
    int j = i - 16384; int h = j >> 7, d = j & 127;
    ws[16384 + j] = W0[(128 + d) * 128 + h] - W0[(256 + d) * 128 + h];
  } else if (i < 49152) {
    int j = i - 32768; int h = j >> 7, d = j & 127;
    ws[32768 + j] = W0[(384 + d) * 128 + h];
  } else if (i < 57344) {
    int j = i - 49152; int g = j >> 7, h = j & 127;
    ((unsigned short*)(ws + 49152))[j] = f2bf(W1[h * 64 + g]);
  }
}

// ---------------------------------------------------------------------------
// Main kernel: one block per b, 256 threads (4 waves), 2 blocks/CU.
// 1) one-shot stage key[b] (200x128) -> bf16 LDS, XOR-swizzled
// 2) build per-block B-frags in regs: W_b = WkT + q_d * WdT  (folds q*k term)
// 3) 13 M-tiles of 16 rows: GEMM1(K=128) -> prelu -> GEMM2 -> prelu -> logits
//    (1 barrier/tile via double-buffered A2/partial)
// 4) softmax, PV
// ---------------------------------------------------------------------------
__global__ __launch_bounds__(256, 2) void din_main(
    const float* __restrict__ query, const float* __restrict__ key,
    const float* __restrict__ val, const int* __restrict__ mask,
    const float* __restrict__ b0, const float* __restrict__ a0,
    const float* __restrict__ b1, const float* __restrict__ a1,
    const float* __restrict__ Wout, const float* __restrict__ bout,
    const float* __restrict__ ws, float* __restrict__ out) {
  const int b = blockIdx.x;
  const int tid = threadIdx.x;
  const int w = tid >> 6;
  const int l = tid & 63;

  __shared__ unsigned short Kb[208 * 128];     // 53248 B, swizzled bf16 key
  __shared__ unsigned short A2t[2][16 * 128];  // 8192 B, dbuf post-prelu H0
  __shared__ float qs[DD];
  __shared__ float qas2[2][H1];
  __shared__ float logitsAll[208];
  __shared__ float eLDS[256];
  __shared__ float partial[2][4][16];
  __shared__ float red4[8];
  __shared__ float red[8 * DD];

  const float* Wqac = ws;
  const float* WkT  = ws + 16384;
  const float* WdT  = ws + 32768;
  const unsigned short* W1tb = (const unsigned short*)(ws + 49152);

  // ---- stage q ----
  if (tid < DD) qs[tid] = query[(size_t)b * DD + tid];

  // ---- one-shot stage key -> bf16 LDS (swizzled) ----
  #pragma unroll 1
  for (int i = 0; i < 25; ++i) {
    int f = i * 256 + tid;            // float4 index, 0..6399
    int row = f >> 5;                 // 0..199
    int d4 = (f & 31) * 4;
    float4 kv = *(const float4*)(key + ((size_t)b * TT + row) * DD + d4);
    ushort4 ku;
    ku.x = f2bf(kv.x); ku.y = f2bf(kv.y); ku.z = f2bf(kv.z); ku.w = f2bf(kv.w);
    char* base = (char*)Kb + row * 256;
    *(ushort4*)(base + ((d4 * 2) ^ ((row & 7) << 4))) = ku;
  }
  {  // zero rows 200..207
    int f = 6400 + tid;
    int row = f >> 5; int d4 = (f & 31) * 4;
    ushort4 z; z.x = z.y = z.z = z.w = 0;
    char* base = (char*)Kb + row * 256;
    *(ushort4*)(base + ((d4 * 2) ^ ((row & 7) << 4))) = z;
  }
  __syncthreads();  // qs + Kb ready

  // ---- build B fragments in registers ----
  // GEMM1: wave w owns n-tiles {2w, 2w+1}; B_b[d][h] = WkT[h][d] + q_d*WdT[h][d]
  short8 B1f[2][4];
  #pragma unroll
  for (int ntl = 0; ntl < 2; ++ntl) {
    int h = (2 * w + ntl) * 16 + (l & 15);
    #pragma unroll
    for (int ks = 0; ks < 4; ++ks) {
      int d0 = ks * 32 + (l >> 4) * 8;
      const float* wk = WkT + h * 128 + d0;
      const float* wd = WdT + h * 128 + d0;
      short8 frag;
      #pragma unroll
      for (int e = 0; e < 8; ++e) {
        float v = wk[e] + qs[d0 + e] * wd[e];
        frag[e] = (short)f2bf(v);
      }
      B1f[ntl][ks] = frag;
    }
  }
  // GEMM2: wave w owns cols g = w*16 + (l&15)
  short8 B2f[4];
  {
    int g = w * 16 + (l & 15);
    #pragma unroll
    for (int ks = 0; ks < 4; ++ks) {
      B2f[ks] = *(const short8*)(W1tb + g * 128 + ks * 32 + (l >> 4) * 8);
    }
  }

  // ---- qA split over 256 threads (each half of d-range) ----
  {
    int h = tid & 127, half = tid >> 7;
    float acc = half ? 0.0f : b0[h];
    const float* wq = Wqac + half * 64 * 128 + h;
    #pragma unroll 8
    for (int d = 0; d < 64; ++d) acc += qs[half * 64 + d] * wq[d * 128];
    qas2[half][h] = acc;
  }

  const int gcol = w * 16 + (l & 15);
  const float b1v = b1[gcol];
  const float wov = Wout[gcol];
  __syncthreads();  // qas2 ready

  // =================== M-tile loop (1 barrier per tile) ===================
  #pragma unroll 1
  for (int mt = 0; mt < 13; ++mt) {
    // ---- GEMM1: 16 rows of Kb @ W_b ----
    floatx4 acc[2];
    acc[0] = (floatx4)(0.0f); acc[1] = (floatx4)(0.0f);
    {
      int trow = mt * 16 + (l & 15);
      int swz = (trow & 7) << 4;
      const char* abase = (const char*)Kb + trow * 256;
      #pragma unroll
      for (int ks = 0; ks < 4; ++ks) {
        short8 af = *(const short8*)(abase + ((ks * 64 + (l >> 4) * 16) ^ swz));
        acc[0] = __builtin_amdgcn_mfma_f32_16x16x32_bf16(af, B1f[0][ks], acc[0], 0, 0, 0);
        acc[1] = __builtin_amdgcn_mfma_f32_16x16x32_bf16(af, B1f[1][ks], acc[1], 0, 0, 0);
      }
    }
    // ---- epilogue 1: +qA, PReLU(a0), write A2t[mt&1] ----
    #pragma unroll
    for (int ntl = 0; ntl < 2; ++ntl) {
      int h = (2 * w + ntl) * 16 + (l & 15);
      float qa = qas2[0][h] + qas2[1][h];
      #pragma unroll
      for (int r = 0; r < 4; ++r) {
        int t_loc = (l >> 4) * 4 + r;
        int t_glob = mt * 16 + t_loc;
        float v = acc[ntl][r] + qa;
        float a = (t_glob < TT) ? a0[t_glob * H1 + h] : 0.0f;
        v = v > 0.0f ? v : a * v;
        int byte = t_loc * 256 + ((h * 2) ^ ((t_loc & 7) << 4));
        *(unsigned short*)((char*)A2t[mt & 1] + byte) = f2bf(v);
      }
    }
    __syncthreads();  // A2t[mt&1] ready; partial[(mt-1)&1] visible

    // ---- combine previous tile's partials -> logits ----
    if (mt > 0 && tid < 16) {
      int t_glob = (mt - 1) * 16 + tid;
      if (t_glob < TT) {
        float lg = bout[0] + partial[(mt - 1) & 1][0][tid] +
                   partial[(mt - 1) & 1][1][tid] +
                   partial[(mt - 1) & 1][2][tid] +
                   partial[(mt - 1) & 1][3][tid];
        int m = mask[(size_t)b * TT + t_glob];
        logitsAll[t_glob] = (m == 0) ? MASK_PAD : lg;
      }
    }

    // ---- GEMM2 ----
    floatx4 acc2 = (floatx4)(0.0f);
    {
      int row = l & 15;
      int swz = (row & 7) << 4;
      const char* abase = (const char*)A2t[mt & 1] + row * 256;
      #pragma unroll
      for (int ks = 0; ks < 4; ++ks) {
        short8 af = *(const short8*)(abase + ((ks * 64 + (l >> 4) * 16) ^ swz));
        acc2 = __builtin_amdgcn_mfma_f32_16x16x32_bf16(af, B2f[ks], acc2, 0, 0, 0);
      }
    }
    // ---- epilogue 2: +b1, PReLU(a1), *Wout, reduce over g -> partial ----
    {
      float p[4];
      #pragma unroll
      for (int r = 0; r < 4; ++r) {
        int t_loc = (l >> 4) * 4 + r;
        int t_glob = mt * 16 + t_loc;
        float x = acc2[r] + b1v;
        float a = (t_glob < TT) ? a1[t_glob * H2 + gcol] : 0.0f;
        x = x > 0.0f ? x : a * x;
        p[r] = x * wov;
      }
      #pragma unroll
      for (int m = 1; m < 16; m <<= 1) {
        #pragma unroll
        for (int r = 0; r < 4; ++r) p[r] += __shfl_xor(p[r], m);
      }
      if ((l & 15) == 0) {
        #pragma unroll
        for (int r = 0; r < 4; ++r) partial[mt & 1][w][(l >> 4) * 4 + r] = p[r];
      }
    }
  }
  __syncthreads();
  // combine last tile (mt=12, buffer 0)
  if (tid < 16) {
    int t_glob = 192 + tid;
    if (t_glob < TT) {
      float lg = bout[0] + partial[0][0][tid] + partial[0][1][tid] +
                 partial[0][2][tid] + partial[0][3][tid];
      int m = mask[(size_t)b * TT + t_glob];
      logitsAll[t_glob] = (m == 0) ? MASK_PAD : lg;
    }
  }
  __syncthreads();

  // =================== softmax ===================
  float lv = (tid < TT) ? logitsAll[tid] : -INFINITY;
  {
    float m = lv;
    #pragma unroll
    for (int off = 32; off >= 1; off >>= 1) m = fmaxf(m, __shfl_xor(m, off));
    if (l == 0) red4[w] = m;
  }
  __syncthreads();
  float mx = fmaxf(fmaxf(red4[0], red4[1]), fmaxf(red4[2], red4[3]));
  float e = (tid < TT) ? __expf(lv - mx) : 0.0f;
  eLDS[tid] = e;
  {
    float s = e;
    #pragma unroll
    for (int off = 32; off >= 1; off >>= 1) s += __shfl_xor(s, off);
    if (l == 0) red4[4 + w] = s;
  }
  __syncthreads();
  float denom = red4[4] + red4[5] + red4[6] + red4[7];
  float inv = 1.0f / denom;

  // =================== PV ===================
  const int group = tid >> 5;
  const int d4 = (tid & 31) * 4;
  const float* vb = val + (size_t)b * TT * DD;
  float4 acc4 = make_float4(0.f, 0.f, 0.f, 0.f);
  #pragma unroll 1
  for (int t = group * 25; t < group * 25 + 25; ++t) {
    float4 v = *(const float4*)(vb + (size_t)t * DD + d4);
    float wt = eLDS[t];
    acc4.x += wt * v.x; acc4.y += wt * v.y;
    acc4.z += wt * v.z; acc4.w += wt * v.w;
  }
  *(float4*)&red[group * DD + d4] = acc4;
  __syncthreads();
  if (tid < DD) {
    float s = 0.0f;
    #pragma unroll
    for (int g = 0; g < 8; ++g) s += red[g * DD + tid];
    out[(size_t)b * DD + tid] = s * inv;
  }
}

extern "C" void kernel_launch(void* const* d_in, const int* in_sizes, int n_in,
                              void* d_out, int out_size, void* d_ws, size_t ws_size,
                              hipStream_t stream) {
  const float* query = (const float*)d_in[0];
  const float* key   = (const float*)d_in[1];
  const float* val   = (const float*)d_in[2];
  const int*   mask  = (const int*)d_in[3];
  const float* W0    = (const float*)d_in[4];
  const float* b0    = (const float*)d_in[5];
  const float* a0    = (const float*)d_in[6];
  const float* W1    = (const float*)d_in[7];
  const float* b1    = (const float*)d_in[8];
  const float* a1    = (const float*)d_in[9];
  const float* Wout  = (const float*)d_in[10];
  const float* bout  = (const float*)d_in[11];
  float* out = (float*)d_out;
  float* ws  = (float*)d_ws;

  hipLaunchKernelGGL(din_fold, dim3(224), dim3(256), 0, stream, W0, W1, ws);
  hipLaunchKernelGGL(din_main, dim3(BB), dim3(256), 0, stream,
                     query, key, val, mask, b0, a0, b1, a1, Wout, bout,
                     ws, out);
}